// Round 3
// baseline (465.580 us; speedup 1.0000x reference)
//
#include <hip/hip_runtime.h>
#include <hip/hip_bf16.h>

#define SLEN 512
#define BATCH 256
#define NIN 300
#define KP 320
#define NG 256
#define NH 64
#define BM 128
#define BN 128
#define BK 64
#define LDP 72   // padded LDS row length (bf16) -> 144B rows, 2-way (free) b128 reads

typedef float f32x4 __attribute__((ext_vector_type(4)));
typedef short s16x8 __attribute__((ext_vector_type(8)));
typedef short s16x4 __attribute__((ext_vector_type(4)));

__device__ __forceinline__ short f2bf(float f) {
  union { float f; unsigned u; } v; v.f = f;
  unsigned r = v.u + 0x7fffu + ((v.u >> 16) & 1u);  // RNE
  return (short)(r >> 16);
}

// Build WcatT[n][k] (bf16, K padded to 320), bcat[n], and WgT[col][k] = W_glt[k][col].
__global__ void prep_w(const float* __restrict__ Wpt0, const float* __restrict__ bpt0,
                       const float* __restrict__ Wpt1, const float* __restrict__ bpt1,
                       const float* __restrict__ Wglt,
                       short* __restrict__ WcatT, float* __restrict__ bcat,
                       float* __restrict__ WgT) {
  int idx = blockIdx.x * 256 + threadIdx.x;
  if (idx < NG * KP) {
    int n = idx / KP, k = idx - n * KP;
    int g = n >> 6, h = n & 63;
    float w = 0.f;
    if (k < NIN) {
      if (h < 32) w = Wpt0[k * 128 + g * 32 + h];
      else        w = 0.5f * Wpt1[(k >> 1) * 128 + g * 32 + (h - 32)];
    }
    WcatT[idx] = f2bf(w);
  }
  if (idx < NG * NH) {  // transpose W_glt (64 x 256) -> WgT (256 x 64)
    int c = idx >> 6, k = idx & 63;
    WgT[idx] = Wglt[k * NG + c];
  }
  if (idx < NG) {
    int g = idx >> 6, h = idx & 63;
    bcat[idx] = (h < 32) ? bpt0[g * 32 + h] : bpt1[g * 32 + h - 32];
  }
}

// C[row][n] = bf16(x[row]) @ WcatT^T + bcat   (row-chunk local)
__global__ __launch_bounds__(256) void gemm_i2h(
    const float* __restrict__ x, const short* __restrict__ WcatT,
    const float* __restrict__ bcat, float* __restrict__ C) {
  __shared__ short As[BM][LDP];
  __shared__ short Bs[BN][LDP];
  const int tid = threadIdx.x;
  const int m0 = blockIdx.x * BM;
  const int n0 = blockIdx.y * BN;
  const int lane = tid & 63;
  const int w = tid >> 6;
  const int wr = w >> 1, wc = w & 1;

  f32x4 acc[4][4];
#pragma unroll
  for (int m = 0; m < 4; ++m)
#pragma unroll
    for (int n = 0; n < 4; ++n) acc[m][n] = (f32x4){0.f, 0.f, 0.f, 0.f};

  const int arow_l = tid >> 4;        // 0..15
  const int acol   = (tid & 15) * 4;  // 0..60
  const int brow_l = tid >> 3;        // 0..31
  const int bcol   = (tid & 7) * 8;   // 0..56

  for (int k0 = 0; k0 < KP; k0 += BK) {
#pragma unroll
    for (int p = 0; p < 8; ++p) {
      int row = p * 16 + arow_l;
      int gk = k0 + acol;
      f32x4 v = (f32x4){0.f, 0.f, 0.f, 0.f};
      if (gk + 3 < NIN)  // 300 = 4*75 so vectors never straddle the boundary
        v = *reinterpret_cast<const f32x4*>(&x[(size_t)(m0 + row) * NIN + gk]);
      s16x4 sv;
      sv[0] = f2bf(v[0]); sv[1] = f2bf(v[1]); sv[2] = f2bf(v[2]); sv[3] = f2bf(v[3]);
      *reinterpret_cast<s16x4*>(&As[row][acol]) = sv;
    }
#pragma unroll
    for (int p = 0; p < 4; ++p) {
      int n = p * 32 + brow_l;
      s16x8 v = *reinterpret_cast<const s16x8*>(&WcatT[(size_t)(n0 + n) * KP + k0 + bcol]);
      *reinterpret_cast<s16x8*>(&Bs[n][bcol]) = v;
    }
    __syncthreads();
#pragma unroll
    for (int ks = 0; ks < 2; ++ks) {
      const int kk = ks * 32 + (lane >> 4) * 8;
      s16x8 a[4], b[4];
#pragma unroll
      for (int m = 0; m < 4; ++m)
        a[m] = *reinterpret_cast<const s16x8*>(&As[wr * 64 + m * 16 + (lane & 15)][kk]);
#pragma unroll
      for (int n = 0; n < 4; ++n)
        b[n] = *reinterpret_cast<const s16x8*>(&Bs[wc * 64 + n * 16 + (lane & 15)][kk]);
#pragma unroll
      for (int m = 0; m < 4; ++m)
#pragma unroll
        for (int n = 0; n < 4; ++n)
          acc[m][n] = __builtin_amdgcn_mfma_f32_16x16x32_bf16(a[m], b[n], acc[m][n], 0, 0, 0);
    }
    __syncthreads();
  }
  const int fc = lane & 15;
  const int fr = (lane >> 4) * 4;
#pragma unroll
  for (int n = 0; n < 4; ++n) {
    int col = n0 + wc * 64 + n * 16 + fc;
    float bias = bcat[col];
#pragma unroll
    for (int m = 0; m < 4; ++m) {
#pragma unroll
      for (int r = 0; r < 4; ++r) {
        int row = m0 + wr * 64 + m * 16 + fr + r;
        C[(size_t)row * NG + col] = acc[m][n][r] + bias;
      }
    }
  }
}

// One workgroup (256 thr = 4 waves) per batch row.
// Wave w, lane l: gate g = l>>4, hidden hidx = 16w + (l&15), gate column = g*64+hidx.
// Weights: 16 named f32x4 (64 VGPRs) from transposed WgT — no array, no demotion.
// Step barrier: lgkmcnt(0) + raw s_barrier (NO vmcnt drain -> hs store / i2h
// prefetch stay in flight across steps). h double-buffered in LDS.
__global__ __launch_bounds__(256, 1) void rec_seq(
    const float* __restrict__ i2h, const float* __restrict__ WgT,
    const float* __restrict__ h_in, const float* __restrict__ c_in,
    float* __restrict__ h_state, float* __restrict__ c_state,
    float* __restrict__ hs_out, float* __restrict__ hT_out, float* __restrict__ cT_out,
    int T, int is_last) {
  const int b = blockIdx.x;
  const int tid = threadIdx.x;
  const int w = tid >> 6;
  const int l = tid & 63;
  const int g = l >> 4;
  const int hidx = w * 16 + (l & 15);
  const int col = g * 64 + hidx;
  __shared__ float h_lds[2][NH];

  const float* wp = WgT + (size_t)col * NH;
#define LOADW(i) f32x4 w##i = *reinterpret_cast<const f32x4*>(wp + (i) * 4);
  LOADW(0) LOADW(1) LOADW(2)  LOADW(3)  LOADW(4)  LOADW(5)  LOADW(6)  LOADW(7)
  LOADW(8) LOADW(9) LOADW(10) LOADW(11) LOADW(12) LOADW(13) LOADW(14) LOADW(15)

  float creg = 0.f;
  if (l < 16) creg = c_in[b * NH + hidx];
  if (tid < NH) h_lds[0][tid] = h_in[b * NH + tid];
  __syncthreads();

  const float* ip = i2h + (size_t)b * NG + col;
  float cur = ip[0];
  float nxt = (T > 1) ? ip[(size_t)NG * BATCH] : 0.f;
  const float mm = (g == 1) ? 2.f : 1.f;

  for (int s = 0; s < T; ++s) {
    float fut = 0.f;
    if (s + 2 < T) fut = ip[(size_t)(s + 2) * NG * BATCH];  // stays in flight across barrier

    const float* hb = h_lds[s & 1];
    f32x4 acc0 = (f32x4){0.f, 0.f, 0.f, 0.f};
    f32x4 acc1 = (f32x4){0.f, 0.f, 0.f, 0.f};
#define DOT(i, A) { f32x4 h4 = *reinterpret_cast<const f32x4*>(hb + (i) * 4); A += h4 * w##i; }
    DOT(0, acc0)  DOT(1, acc1)  DOT(2, acc0)  DOT(3, acc1)
    DOT(4, acc0)  DOT(5, acc1)  DOT(6, acc0)  DOT(7, acc1)
    DOT(8, acc0)  DOT(9, acc1)  DOT(10, acc0) DOT(11, acc1)
    DOT(12, acc0) DOT(13, acc1) DOT(14, acc0) DOT(15, acc1)
    f32x4 accv = acc0 + acc1;
    float pre = cur + ((accv[0] + accv[1]) + (accv[2] + accv[3]));

    // sigmoid for f,i,o; tanh (=2*sigmoid(2x)-1) for g; one exp either way
    float xx = fminf(fmaxf(pre, -30.f), 30.f);
    float e = __expf(-mm * xx);
    float y = 1.f / (1.f + e);
    float act = (g == 1) ? (2.f * y - 1.f) : y;

    // lanes 0..15 (g==0, holding f) gather g,i,o from lanes +16,+32,+48
    float g_ = __shfl(act, l + 16);
    float i_ = __shfl(act, l + 32);
    float o_ = __shfl(act, l + 48);

    if (l < 16) {
      float c1 = act * creg + i_ * g_;
      creg = c1;
      float ct = fminf(fmaxf(c1, -15.f), 15.f);
      float e2 = __expf(-2.f * ct);
      float th = (1.f - e2) / (1.f + e2);
      float h1 = o_ * th;
      h_lds[(s + 1) & 1][hidx] = h1;
      hs_out[((size_t)s * BATCH + b) * NH + hidx] = h1;  // fire-and-forget
    }
    // order the ds_write only; global store + prefetch loads stay outstanding
    asm volatile("s_waitcnt lgkmcnt(0)" ::: "memory");
    __builtin_amdgcn_s_barrier();
    cur = nxt; nxt = fut;
  }
  if (l < 16) {
    h_state[b * NH + hidx] = h_lds[T & 1][hidx];
    c_state[b * NH + hidx] = creg;
    if (is_last) {
      hT_out[b * NH + hidx] = h_lds[T & 1][hidx];
      cT_out[b * NH + hidx] = creg;
    }
  }
}

// decoded[idx][j] = hs[idx][:] @ Wdec[:,j] + bdec[j], idx = s*BATCH+b
__global__ __launch_bounds__(256) void decode(
    const float* __restrict__ hs, const float* __restrict__ Wdec,
    const float* __restrict__ bdec, float* __restrict__ out, int n) {
  __shared__ float wl[NH * 3];
  __shared__ float bl[3];
  const int tid = threadIdx.x;
  if (tid < NH * 3) wl[tid] = Wdec[tid];
  if (tid < 3) bl[tid] = bdec[tid];
  __syncthreads();
  int idx = blockIdx.x * 256 + tid;
  if (idx >= n) return;
  const float* hp = hs + (size_t)idx * NH;
  float d0 = 0.f, d1 = 0.f, d2 = 0.f;
#pragma unroll
  for (int k = 0; k < NH; k += 4) {
    f32x4 h4 = *reinterpret_cast<const f32x4*>(&hp[k]);
#pragma unroll
    for (int j = 0; j < 4; ++j) {
      d0 += h4[j] * wl[(k + j) * 3 + 0];
      d1 += h4[j] * wl[(k + j) * 3 + 1];
      d2 += h4[j] * wl[(k + j) * 3 + 2];
    }
  }
  out[(size_t)idx * 3 + 0] = d0 + bl[0];
  out[(size_t)idx * 3 + 1] = d1 + bl[1];
  out[(size_t)idx * 3 + 2] = d2 + bl[2];
}

extern "C" void kernel_launch(void* const* d_in, const int* in_sizes, int n_in,
                              void* d_out, int out_size, void* d_ws, size_t ws_size,
                              hipStream_t stream) {
  const float* x    = (const float*)d_in[0];
  const float* h0   = (const float*)d_in[1];
  const float* c0   = (const float*)d_in[2];
  const float* Wpt0 = (const float*)d_in[3];
  const float* bpt0 = (const float*)d_in[4];
  const float* Wpt1 = (const float*)d_in[5];
  const float* bpt1 = (const float*)d_in[6];
  const float* Wglt = (const float*)d_in[7];
  const float* Wdec = (const float*)d_in[8];
  const float* bdec = (const float*)d_in[9];
  float* out = (float*)d_out;

  char* ws = (char*)d_ws;
  short* WcatT   = (short*)(ws);            // 320*256*2 = 163840 B
  float* bcat    = (float*)(ws + 163840);   // 1 KB
  float* WgT     = (float*)(ws + 196608);   // 64 KB (256 x 64 f32, transposed W_glt)
  float* h_state = (float*)(ws + 262144);   // 64 KB
  float* c_state = (float*)(ws + 327680);   // 64 KB
  const size_t base = 393216;

  // per-step chunk bytes: i2h (256*256*4) + hs (256*64*4)
  const size_t i2h_step = (size_t)BATCH * NG * 4;
  const size_t hs_step  = (size_t)BATCH * NH * 4;
  size_t avail = (ws_size > base) ? ws_size - base : 0;
  int T = (int)(avail / (i2h_step + hs_step));
  if (T > SLEN) T = SLEN;
  if (T < 1) T = 1;

  float* i2h = (float*)(ws + base);
  float* hs  = (float*)(ws + base + (size_t)T * i2h_step);

  prep_w<<<dim3((NG * KP + 255) / 256), dim3(256), 0, stream>>>(
      Wpt0, bpt0, Wpt1, bpt1, Wglt, WcatT, bcat, WgT);

  for (int t0 = 0; t0 < SLEN; t0 += T) {
    int Tc = (SLEN - t0 < T) ? (SLEN - t0) : T;
    dim3 g(Tc * BATCH / BM, NG / BN);
    gemm_i2h<<<g, dim3(256), 0, stream>>>(
        x + (size_t)t0 * BATCH * NIN, WcatT, bcat, i2h);
    rec_seq<<<dim3(BATCH), dim3(256), 0, stream>>>(
        i2h, WgT,
        (t0 == 0) ? h0 : h_state, (t0 == 0) ? c0 : c_state,
        h_state, c_state, hs,
        out + (size_t)SLEN * BATCH * 3,
        out + (size_t)SLEN * BATCH * 3 + BATCH * NH,
        Tc, (t0 + Tc >= SLEN) ? 1 : 0);
    decode<<<dim3((Tc * BATCH + 255) / 256), dim3(256), 0, stream>>>(
        hs, Wdec, bdec, out + (size_t)t0 * BATCH * 3, Tc * BATCH);
  }
}